// Round 3
// baseline (203.399 us; speedup 1.0000x reference)
//
#include <hip/hip_runtime.h>

#define NB 32
#define NT 512
#define ND 384
#define DUR_MAX 8
#define MAX_OUT (NT * (DUR_MAX - 1))   // 3584
#define NV (ND / 4)                    // 96 float4 per row
#define NWIN 16                        // output windows per batch
#define WPOS (MAX_OUT / NWIN)          // 224 output positions per block
#define NBLK (NB * NWIN)               // 512 blocks (2 per CU, %8==0)
#define VPT (WPOS * NV / NT)           // 42 float4 per thread

// Single fused kernel. Race-proof LDS table build:
//   1) every ridx slot set to -1 by exactly one thread,
//   2) (two barriers pass — the scan's),
//   3) scatter overwrites only valid slots (disjoint per-thread intervals).
// Gather load address is clamped so even speculative loads stay in-bounds.
__global__ __launch_bounds__(NT) void lr_fused(
    const int* __restrict__ dur, const float4* __restrict__ in,
    float4* __restrict__ out)
{
    __shared__ int wsum[NT / 64];
    __shared__ int ridx[WPOS];

    // XCD swizzle: 64 consecutive logical blocks (= 4 batches) per XCD
    // -> each XCD reads only 3 MB of input (L2-resident). Bijective (512%8==0).
    const unsigned bid = blockIdx.x;
    const unsigned l   = (bid & 7u) * (NBLK / 8u) + (bid >> 3);
    const int b  = (int)(l >> 4);       // batch
    const int wb = (int)(l & 15u);      // window within batch
    const int p0 = wb * WPOS;

    const int t    = threadIdx.x;
    const int lane = t & 63;
    const int w    = t >> 6;

    // (1) sentinel-init the whole window BEFORE the scan barriers
    if (t < WPOS) ridx[t] = -1;

    int d = dur[b * NT + t];
    d = d > 0 ? d : 0;                  // patched = max(round(1.0*d),0) == max(d,0)

    // wave-level inclusive shfl scan (6 steps), then 8-wave combine
    int v = d;
    #pragma unroll
    for (int off = 1; off < 64; off <<= 1) {
        int u = __shfl_up(v, off);
        if (lane >= off) v += u;
    }
    if (lane == 63) wsum[w] = v;
    __syncthreads();
    if (t == 0) {
        int acc = 0;
        #pragma unroll
        for (int i = 0; i < NT / 64; ++i) { acc += wsum[i]; wsum[i] = acc; }
    }
    __syncthreads();
    const int cum   = v + (w ? wsum[w - 1] : 0);
    const int start = cum - d;          // exclusive prefix

    // (3) scatter source float4-base into this window's slots; intervals
    // [start, start+d) are disjoint across threads and all < total, so
    // every write target is unique; tail keeps the -1 from step (1).
    int lo = start - p0;        if (lo < 0) lo = 0;
    int hi = start + d - p0;    if (hi > WPOS) hi = WPOS;
    const int src = (b * NT + t) * NV;
    for (int j = lo; j < hi; ++j) ridx[j] = src;
    __syncthreads();

    // coalesced copy: 224 rows x 96 float4 = 21504 float4 / 512 thr = 42 each
    float4* ob = out + ((size_t)b * MAX_OUT + p0) * NV;
    for (int i = 0; i < VPT; ++i) {
        const int g = i * NT + t;
        const int r = g / NV;           // compile-time magic-mul
        const int c = g - r * NV;
        const int s = ridx[r];          // LDS, broadcast within wave
        const int sa = s >= 0 ? s : 0;  // clamp: speculative load stays in-bounds
        const float4 ld = in[sa + c];
        float4 val = make_float4(0.f, 0.f, 0.f, 0.f);
        if (s >= 0) val = ld;
        ob[g] = val;
    }
}

extern "C" void kernel_launch(void* const* d_in, const int* in_sizes, int n_in,
                              void* d_out, int out_size, void* d_ws, size_t ws_size,
                              hipStream_t stream)
{
    const float* x   = (const float*)d_in[0];
    const int*   dur = (const int*)d_in[1];
    float* out = (float*)d_out;

    lr_fused<<<NBLK, NT, 0, stream>>>(dur, (const float4*)x, (float4*)out);
}